// Round 2
// baseline (2987.954 us; speedup 1.0000x reference)
//
#include <hip/hip_runtime.h>
#include <math.h>

#define B_ 1024
#define T_ 128
#define H_ 2048
#define C_ 10

typedef __bf16 bf16_t;
typedef __bf16 bf16x8 __attribute__((ext_vector_type(8)));
typedef __bf16 bf16x4 __attribute__((ext_vector_type(4)));
typedef float f32x4 __attribute__((ext_vector_type(4)));

// Static device storage: bf16 h ping-pong (8 MB), bf16 W_hh^T (8 MB),
// transposed x (512 KB), per-(t,bm) readiness counters (XCD-local handoff).
__device__ __align__(16) bf16_t g_hb[2][(size_t)B_ * H_];
__device__ __align__(16) bf16_t g_whhT[(size_t)H_ * H_];
__device__ __align__(16) float  g_xT[(size_t)T_ * B_];   // [t][row]
__device__ int g_cnt[T_ * 8];   // [t][bm]; t=0 seeded to 32 by rnn_init

// AUX: cache policy. 0 = default; 1 = sc0 (force L1 miss -> read XCD L2).
template <int AUX>
__device__ __forceinline__ void gload16(const bf16_t* g, bf16_t* l) {
    __builtin_amdgcn_global_load_lds(
        (const __attribute__((address_space(1))) void*)g,
        (__attribute__((address_space(3))) void*)l, 16, 0, AUX);
}

// Counted-vmcnt barrier: retire oldest pipeline stage without draining.
template <int VM>
__device__ __forceinline__ void wait_vm_barrier() {
    asm volatile("s_waitcnt vmcnt(%0)\n\ts_barrier" :: "n"(VM) : "memory");
}

// MFMA via inline asm with B pinned to AGPRs ("a" constraint): this is what
// guarantees the persistent W_hh^T fragments live in the accumulator file
// instead of being spilled to scratch (round-1 failure: VGPR_Count=180).
#define MMA(C, A, Bf)                                                    \
    asm("v_mfma_f32_16x16x32_bf16 %0, %1, %2, %0"                        \
        : "+v"(C) : "v"(A), "a"(Bf))

// One-time: W_hhT[n][k] = bf16(W_hh[k][n]) — B operand must be K-contiguous.
__global__ __launch_bounds__(256) void prep_whhT(const float* __restrict__ Whh) {
    __shared__ float tile[32][33];
    const int i  = threadIdx.x >> 3;
    const int j4 = (threadIdx.x & 7) * 4;
    const int r0 = blockIdx.y * 32;
    const int c0 = blockIdx.x * 32;
    f32x4 v = *(const f32x4*)(Whh + (size_t)(r0 + i) * H_ + c0 + j4);
    tile[i][j4 + 0] = v[0]; tile[i][j4 + 1] = v[1];
    tile[i][j4 + 2] = v[2]; tile[i][j4 + 3] = v[3];
    __syncthreads();
    bf16x4 o;
#pragma unroll
    for (int r = 0; r < 4; ++r) o[r] = (bf16_t)tile[j4 + r][i];
    *(bf16x4*)&g_whhT[(size_t)(c0 + i) * H_ + r0 + j4] = o;
}

// One-time: g_xT[t][row] = x[row][t] (f32). Epilogue then loads f32x4 that
// broadcast across lanes, instead of 32 strided scalar loads per lane.
__global__ __launch_bounds__(256) void xpose(const float* __restrict__ x) {
    const int g   = blockIdx.x * 256 + threadIdx.x;   // 32768 threads
    const int row = g >> 5;                           // 0..1023
    const int t0  = (g & 31) * 4;
    f32x4 v = *(const f32x4*)(x + (size_t)row * T_ + t0);
#pragma unroll
    for (int q = 0; q < 4; ++q) g_xT[(size_t)(t0 + q) * B_ + row] = v[q];
}

// t = 0: h = tanh(x[:,0]*W_hx + b_h); also (re)initialize the counters.
__global__ __launch_bounds__(256) void rnn_init(const float* __restrict__ x,
                                                const float* __restrict__ Whx,
                                                const float* __restrict__ bh) {
    if (blockIdx.x == 0) {
        for (int i = threadIdx.x; i < T_ * 8; i += 256)
            g_cnt[i] = (i < 8) ? 32 : 0;   // g_cnt[0][*] = 32 (h0 ready)
    }
    const int gid = blockIdx.x * 256 + threadIdx.x;
    const int row = gid >> 9;
    const int col = (gid & 511) << 2;
    const float xv = x[(size_t)row * T_];
    f32x4 w = *(const f32x4*)&Whx[col];
    f32x4 b = *(const f32x4*)&bh[col];
    bf16x4 o;
#pragma unroll
    for (int j = 0; j < 4; ++j) o[j] = (bf16_t)tanhf(fmaf(xv, w[j], b[j]));
    *(bf16x4*)&g_hb[0][(size_t)row * H_ + col] = o;
}

// Persistent RNN, XCD-local sync. v3: AGPR-stationary B + 2-way K-split.
//  - W_hh^T fragments (64 x bf16x8 = 256 regs/lane) pinned in AGPRs via
//    asm "a" constraints; zero per-step B traffic anywhere.
//  - Waves retiled (nh, kh): 128 rows x 32 cols x 1024 K each. Each A-frag
//    feeds 2 MFMAs (jn=0,1) -> block LDS A-reads halve to 1 MB/step.
//  - K-halves reduced across wave pairs via padded LDS region (+1 barrier).
//  - A ring: 3 slots x 32 KB (lo+hi K-half per slot), steady vmcnt(8).
__global__ __launch_bounds__(256, 1) void rnn_persist(const float* __restrict__ x,
                                                      const float* __restrict__ Whx,
                                                      const float* __restrict__ bh) {
    extern __shared__ __align__(16) bf16_t smem[];
    bf16_t* As  = smem;                         // 3 slots x 16384 bf16 = 96 KB
    float*  red = (float*)(smem + 3 * 16384);   // 4 regions x 2176 f32 = 34 KB

    const int tid  = threadIdx.x;
    const int lane = tid & 63;
    const int wave = tid >> 6;
    const int li  = blockIdx.x;
    const int bm  = li & 7;                          // == XCD (blk%8 map)
    const int bn  = li >> 3;                         // 0..31

    const int nh  = wave >> 1;                       // col half (32 cols)
    const int kh  = wave & 1;                        // K half (1024)
    const int khs = kh * 8192;                       // sub-slot offset (elems)

    const int fr = lane & 15, fq = lane >> 4;

    // ---- one-time: persistent B in AGPRs.
    // col = bn*64 + nh*32 + jn*16 + fr ; k = kh*1024 + it*64 + kk*32 + fq*8
    bf16x8 breg[16][2][2];
    {
        const bf16_t* gw = g_whhT + (size_t)(bn * 64 + nh * 32 + fr) * H_
                         + kh * 1024 + fq * 8;
#pragma unroll
        for (int it = 0; it < 16; ++it)
#pragma unroll
            for (int jn = 0; jn < 2; ++jn)
#pragma unroll
                for (int kk = 0; kk < 2; ++kk)
                    breg[it][jn][kk] =
                        *(const bf16x8*)(gw + (size_t)jn * 16 * H_ + it * 64 + kk * 32);
    }

    // A staging: linear slot s holds row s>>3, lds-chunk s&7;
    // global chunk = (s&7) ^ (row&7)  (8-row spread -> conflict-free reads).
    const int rA = tid >> 3;                         // 0..31
    const int cg = (tid & 7) ^ (rA & 7);
    const size_t aofsg = (size_t)(bm * 128 + rA) * H_ + cg * 8;

    // slot = [lo 8192: k=it*64][hi 8192: k=1024+it*64], rows 0..127 each
#define ISSUE_S(SLOT)                                                         \
    do {                                                                      \
        bf16_t* l = As + (SLOT) * 16384;                                      \
        gload16<1>(gpa,                  l + tid * 8);                        \
        gload16<1>(gpa + 32 * H_,        l + (tid + 256) * 8);                \
        gload16<1>(gpa + 64 * H_,        l + (tid + 512) * 8);                \
        gload16<1>(gpa + 96 * H_,        l + (tid + 768) * 8);                \
        gload16<1>(gpa + 1024,           l + 8192 + tid * 8);                 \
        gload16<1>(gpa + 1024 + 32 * H_, l + 8192 + (tid + 256) * 8);         \
        gload16<1>(gpa + 1024 + 64 * H_, l + 8192 + (tid + 512) * 8);         \
        gload16<1>(gpa + 1024 + 96 * H_, l + 8192 + (tid + 768) * 8);         \
        gpa += 64;                                                            \
    } while (0)

    // frag read bases (elems): row fr, de-swizzled chunk (kk*4+fq)^(fr&7)
    const int cb[2] = { fr * 64 + ((0 + fq) ^ (fr & 7)) * 8,
                        fr * 64 + ((4 + fq) ^ (fr & 7)) * 8 };

    f32x4 acc[8][2];

    // IT must be a literal (breg is AGPR-resident, compile-time indexed).
#define COMPUTE_S(SLOT, IT)                                                   \
    do {                                                                      \
        const bf16_t* ab = As + (SLOT) * 16384 + khs;                         \
        _Pragma("unroll")                                                     \
        for (int kk = 0; kk < 2; ++kk) {                                      \
            bf16x8 af[8];                                                     \
            _Pragma("unroll")                                                 \
            for (int m = 0; m < 8; ++m)                                       \
                af[m] = *(const bf16x8*)(ab + m * 1024 + cb[kk]);             \
            _Pragma("unroll")                                                 \
            for (int m = 0; m < 8; ++m) {                                     \
                MMA(acc[m][0], af[m], breg[IT][0][kk]);                       \
                MMA(acc[m][1], af[m], breg[IT][1][kk]);                       \
            }                                                                 \
        }                                                                     \
    } while (0)

#define ITER(ISS, CMP, IT)                                                    \
    do { wait_vm_barrier<8>(); ISSUE_S(ISS); COMPUTE_S(CMP, IT); } while (0)

    // epilogue constants (step-invariant)
    float wv[2], bv[2];
#pragma unroll
    for (int jn = 0; jn < 2; ++jn) {
        const int col = bn * 64 + nh * 32 + jn * 16 + fr;
        wv[jn] = Whx[col];
        bv[jn] = bh[col];
    }

#pragma unroll 1
    for (int t = 1; t < T_; ++t) {
        const bf16_t* __restrict__ Abuf = g_hb[(t - 1) & 1];
        bf16_t* __restrict__ hn = g_hb[t & 1];
        const bf16_t* gpa = Abuf + aofsg;

#pragma unroll
        for (int m = 0; m < 8; ++m)
#pragma unroll
            for (int jn = 0; jn < 2; ++jn) acc[m][jn] = (f32x4)(0.f);

        // wait until all 32 same-XCD writers of h-rows bm finished step t-1
        if (tid == 0) {
            while (__hip_atomic_load(&g_cnt[(t - 1) * 8 + bm], __ATOMIC_RELAXED,
                                     __HIP_MEMORY_SCOPE_AGENT) != 32)
                __builtin_amdgcn_s_sleep(2);
        }
        __syncthreads();          // no agent fence: sc0 A-loads read fresh L2

        ISSUE_S(0); ISSUE_S(1);   // iters 0,1 in flight (16 loads)

        // 16 iters, 3-slot ring, 2 slots in flight, steady vmcnt(8).
        ITER(2,0,0);  ITER(0,1,1);  ITER(1,2,2);  ITER(2,0,3);
        ITER(0,1,4);  ITER(1,2,5);  ITER(2,0,6);  ITER(0,1,7);
        ITER(1,2,8);  ITER(2,0,9);  ITER(0,1,10); ITER(1,2,11);
        ITER(2,0,12); ITER(0,1,13);
        wait_vm_barrier<8>(); COMPUTE_S(2, 14);
        wait_vm_barrier<0>(); COMPUTE_S(0, 15);

        // MFMA->VALU/DS hazard fence (asm MFMAs are opaque to the compiler)
        asm volatile("s_nop 7\n\ts_nop 7\n\ts_nop 3" ::: );

        // ---- cross-wave K-half reduction (pairs (nh,0)<->(nh,1)).
        // Each wave writes its NON-kept m-half, reads partner's for its kept
        // half. Region [nh][half]: f32 [32 cols][68] (pad 68 -> ~no conflicts)
        {
            float* wr = red + (size_t)(nh * 2 + (1 - kh)) * 2176;
#pragma unroll
            for (int mo = 0; mo < 4; ++mo) {
                const int mm = (1 - kh) * 4 + mo;
#pragma unroll
                for (int jn = 0; jn < 2; ++jn)
                    *(f32x4*)(wr + (jn * 16 + fr) * 68 + mo * 16 + fq * 4) =
                        acc[mm][jn];
            }
        }
        __syncthreads();
        {
            const float* rr = red + (size_t)(nh * 2 + kh) * 2176;
#pragma unroll
            for (int mo = 0; mo < 4; ++mo) {
                const int mk = kh * 4 + mo;
#pragma unroll
                for (int jn = 0; jn < 2; ++jn)
                    acc[mk][jn] += *(const f32x4*)(rr + (jn * 16 + fr) * 68 +
                                                   mo * 16 + fq * 4);
            }
        }

        // epilogue: + x_t*W_hx + b_h, tanh, bf16 store (kept rows only)
#pragma unroll
        for (int mo = 0; mo < 4; ++mo) {
            const int mk   = kh * 4 + mo;
            const int row0 = bm * 128 + mk * 16 + fq * 4;
            const f32x4 xq = *(const f32x4*)(g_xT + (size_t)t * B_ + row0);
#pragma unroll
            for (int jn = 0; jn < 2; ++jn) {
                const int col = bn * 64 + nh * 32 + jn * 16 + fr;
#pragma unroll
                for (int r = 0; r < 4; ++r)
                    hn[(size_t)(row0 + r) * H_ + col] =
                        (bf16_t)tanhf(acc[mk][jn][r] + xq[r] * wv[jn] + bv[jn]);
            }
        }

        // publish: drain this wave's stores to L2, join waves, bump counter.
        asm volatile("s_waitcnt vmcnt(0)" ::: "memory");
        __syncthreads();
        if (tid == 0)
            __hip_atomic_fetch_add(&g_cnt[t * 8 + bm], 1, __ATOMIC_RELAXED,
                                   __HIP_MEMORY_SCOPE_AGENT);
    }
#undef ITER
#undef COMPUTE_S
#undef ISSUE_S
}

// p = h_T @ W_ph + b_p : one wave per batch row, fp32 accumulate.
__global__ __launch_bounds__(64) void rnn_proj(const float* __restrict__ Wph,
                                               const float* __restrict__ bp,
                                               float* __restrict__ out, int sb) {
    const int b = blockIdx.x;
    const int l = threadIdx.x;
    const bf16_t* h = g_hb[sb] + (size_t)b * H_;
    float acc[C_];
#pragma unroll
    for (int c = 0; c < C_; ++c) acc[c] = 0.f;
    for (int k = l; k < H_; k += 64) {
        const float hv = (float)h[k];
#pragma unroll
        for (int c = 0; c < C_; ++c)
            acc[c] = fmaf(hv, Wph[k * C_ + c], acc[c]);
    }
#pragma unroll
    for (int off = 32; off > 0; off >>= 1)
#pragma unroll
        for (int c = 0; c < C_; ++c) acc[c] += __shfl_down(acc[c], off);
    if (l == 0) {
#pragma unroll
        for (int c = 0; c < C_; ++c) out[b * C_ + c] = acc[c] + bp[c];
    }
}

extern "C" void kernel_launch(void* const* d_in, const int* in_sizes, int n_in,
                              void* d_out, int out_size, void* d_ws, size_t ws_size,
                              hipStream_t stream) {
    const float* x   = (const float*)d_in[0];   // [1024,128]
    const float* Whx = (const float*)d_in[1];   // [1,2048]
    const float* Whh = (const float*)d_in[2];   // [2048,2048]
    const float* bh  = (const float*)d_in[3];   // [2048]
    const float* Wph = (const float*)d_in[4];   // [2048,10]
    const float* bp  = (const float*)d_in[5];   // [1,10]
    float* out = (float*)d_out;                 // [1024,10]

    static bool attr_set = false;
    if (!attr_set) {
        hipFuncSetAttribute((const void*)rnn_persist,
                            hipFuncAttributeMaxDynamicSharedMemorySize, 147456);
        attr_set = true;
    }

    prep_whhT<<<dim3(64, 64), 256, 0, stream>>>(Whh);
    xpose<<<(B_ * T_ / 4) / 256, 256, 0, stream>>>(x);
    rnn_init<<<(B_ * H_ / 4) / 256, 256, 0, stream>>>(x, Whx, bh);
    rnn_persist<<<256, 256, 133120, stream>>>(x, Whx, bh);
    rnn_proj<<<B_, 64, 0, stream>>>(Wph, bp, out, (T_ - 1) & 1);
}

// Round 3
// 2797.250 us; speedup vs baseline: 1.0682x; 1.0682x over previous
//
#include <hip/hip_runtime.h>
#include <math.h>

#define B_ 1024
#define T_ 128
#define H_ 2048
#define C_ 10

typedef __bf16 bf16_t;
typedef __bf16 bf16x8 __attribute__((ext_vector_type(8)));
typedef __bf16 bf16x4 __attribute__((ext_vector_type(4)));
typedef float f32x4 __attribute__((ext_vector_type(4)));

// Static device storage: bf16 h ping-pong (8 MB), bf16 W_hh^T (8 MB),
// per-(t,bm,bn) writer-done flags (fine-grained XCD-local handoff).
__device__ __align__(16) bf16_t g_hb[2][(size_t)B_ * H_];
__device__ __align__(16) bf16_t g_whhT[(size_t)H_ * H_];
__device__ int g_flag[T_ * 8 * 32];   // [t][bm][bn]; t=0 seeded by rnn_init

// AUX: cache policy. 0 = default; 1 = sc0 (force L1 miss -> read XCD L2).
template <int AUX>
__device__ __forceinline__ void gload16(const bf16_t* g, bf16_t* l) {
    __builtin_amdgcn_global_load_lds(
        (const __attribute__((address_space(1))) void*)g,
        (__attribute__((address_space(3))) void*)l, 16, 0, AUX);
}

// Counted-vmcnt barrier: retire oldest pipeline stage without draining.
template <int VM>
__device__ __forceinline__ void wait_vm_barrier() {
    asm volatile("s_waitcnt vmcnt(%0)\n\ts_barrier" :: "n"(VM) : "memory");
}

// One-time: W_hhT[n][k] = bf16(W_hh[k][n]) — B operand must be K-contiguous.
__global__ __launch_bounds__(256) void prep_whhT(const float* __restrict__ Whh) {
    __shared__ float tile[32][33];
    const int i  = threadIdx.x >> 3;
    const int j4 = (threadIdx.x & 7) * 4;
    const int r0 = blockIdx.y * 32;
    const int c0 = blockIdx.x * 32;
    f32x4 v = *(const f32x4*)(Whh + (size_t)(r0 + i) * H_ + c0 + j4);
    tile[i][j4 + 0] = v[0]; tile[i][j4 + 1] = v[1];
    tile[i][j4 + 2] = v[2]; tile[i][j4 + 3] = v[3];
    __syncthreads();
    bf16x4 o;
#pragma unroll
    for (int r = 0; r < 4; ++r) o[r] = (bf16_t)tile[j4 + r][i];
    *(bf16x4*)&g_whhT[(size_t)(c0 + i) * H_ + r0 + j4] = o;
}

// t = 0: h = tanh(x[:,0]*W_hx + b_h); also (re)initialize the flags.
__global__ __launch_bounds__(256) void rnn_init(const float* __restrict__ x,
                                                const float* __restrict__ Whx,
                                                const float* __restrict__ bh) {
    if (blockIdx.x == 0) {
        for (int i = threadIdx.x; i < T_ * 256; i += 256)
            g_flag[i] = (i < 256) ? 1 : 0;   // g_flag[0][*][*] = 1 (h0 ready)
    }
    const int gid = blockIdx.x * 256 + threadIdx.x;
    const int row = gid >> 9;
    const int col = (gid & 511) << 2;
    const float xv = x[(size_t)row * T_];
    f32x4 w = *(const f32x4*)&Whx[col];
    f32x4 b = *(const f32x4*)&bh[col];
    bf16x4 o;
#pragma unroll
    for (int j = 0; j < 4; ++j) o[j] = (bf16_t)tanhf(fmaf(xv, w[j], b[j]));
    *(bf16x4*)&g_hb[0][(size_t)row * H_ + col] = o;
}

// Persistent RNN. v4 = v1 structure (proven 2464 us) with ONE change:
// fine-grained per-writer synchronization instead of the 32-block XCD
// rendezvous. Writer (bm,bn) publishes flag[t][bm][bn] after storing its
// 64 h-columns; reader (bm,bn') consumes K-chunks rotated c=(bn'+j)&31,
// polling flags per 8-chunk phase. Flag loads are pre-issued >=3 iters
// before their check: in-order vmem retirement means by CHECK time they
// are provably retired (younger staged loads already waited on), so the
// hand-counted vmcnt schedule is unchanged and no extra drain occurs.
// The straggler writer's chunk is consumed LAST (latency hidden behind
// ~24 chunks of compute) -> convoy max() over 32 blocks becomes ~mean().
__global__ __launch_bounds__(256, 1) void rnn_persist(const float* __restrict__ x,
                                                      const float* __restrict__ Whx,
                                                      const float* __restrict__ bh) {
    extern __shared__ __align__(16) bf16_t smem[];
    bf16_t* As = smem;                 // 6 stages x 8192 elems (16 KB)
    bf16_t* Bs = smem + 6 * 8192;      // 6 stages x 4096 elems (8 KB)

    const int tid  = threadIdx.x;
    const int lane = tid & 63;
    const int wave = tid >> 6;
    const int li  = blockIdx.x;
    const int bm  = li & 7;                          // == XCD (blk%8 map)
    const int bn  = li >> 3;                         // 0..31

    const int wm = (wave & 1) * 64, wn = (wave >> 1) * 32;
    const int fr = lane & 15, fq = lane >> 4;

    // Staging: linear slot s holds row s>>3, lds-chunk s&7;
    // global chunk = (s&7) ^ (row&7)  (8-row spread -> 2-way frag reads).
    const int rA = tid >> 3;                         // 0..31
    const int cg = (tid & 7) ^ (rA & 7);
    const size_t aofsg = (size_t)(bm * 128 + rA) * H_ + cg * 8;
    const bf16_t* const gb0 = g_whhT + (size_t)(bn * 64 + rA) * H_ + cg * 8;

    // Issue both operands of K-chunk (bn+J)&31 into ring slot SLOT.
#define ISSUE_AB(SLOT, J)                                                 \
    do {                                                                  \
        const int c_ = (bn + (J)) & 31;                                   \
        const bf16_t* ga_ = Abuf + aofsg + c_ * 64;                       \
        const bf16_t* gb_ = gb0 + c_ * 64;                                \
        gload16<1>(ga_,           As + (SLOT) * 8192 + tid * 8);          \
        gload16<1>(ga_ + 32 * H_, As + (SLOT) * 8192 + (tid + 256) * 8);  \
        gload16<1>(ga_ + 64 * H_, As + (SLOT) * 8192 + (tid + 512) * 8);  \
        gload16<1>(ga_ + 96 * H_, As + (SLOT) * 8192 + (tid + 768) * 8);  \
        gload16<0>(gb_,           Bs + (SLOT) * 4096 + tid * 8);          \
        gload16<0>(gb_ + 32 * H_, Bs + (SLOT) * 4096 + (tid + 256) * 8);  \
    } while (0)

    // frag offsets (elems): row*64 + ((cc*4+fq) ^ (row&7))*8; row&7 == fr&7.
    const int xr0 = (fq ^ (fr & 7)) * 8;
    const int xr1 = ((4 + fq) ^ (fr & 7)) * 8;
    int aoff[4][2], boff[2][2];
#pragma unroll
    for (int i = 0; i < 4; ++i) {
        aoff[i][0] = (wm + i * 16 + fr) * 64 + xr0;
        aoff[i][1] = (wm + i * 16 + fr) * 64 + xr1;
    }
#pragma unroll
    for (int j = 0; j < 2; ++j) {
        boff[j][0] = (wn + j * 16 + fr) * 64 + xr0;
        boff[j][1] = (wn + j * 16 + fr) * 64 + xr1;
    }

#define COMPUTE(SLOT)                                                       \
    {                                                                       \
        _Pragma("unroll")                                                   \
        for (int cc = 0; cc < 2; ++cc) {                                    \
            bf16x8 af[4], bfv[2];                                           \
            _Pragma("unroll")                                               \
            for (int j = 0; j < 2; ++j)                                     \
                bfv[j] = *(const bf16x8*)(Bs + (SLOT) * 4096 + boff[j][cc]);\
            _Pragma("unroll")                                               \
            for (int i = 0; i < 4; ++i)                                     \
                af[i] = *(const bf16x8*)(As + (SLOT) * 8192 + aoff[i][cc]); \
            _Pragma("unroll")                                               \
            for (int i = 0; i < 4; ++i)                                     \
                _Pragma("unroll")                                           \
                for (int j = 0; j < 2; ++j)                                 \
                    acc[i][j] = __builtin_amdgcn_mfma_f32_16x16x32_bf16(    \
                        af[i], bfv[j], acc[i][j], 0, 0, 0);                 \
        }                                                                   \
    }

    // Per-phase readiness poll: lanes l poll flag of writer (bn+PH*8+(l&7)).
    // PREPOLL issues the load early; CHECKF consumes it (spin only if a
    // writer is genuinely behind).
    const int* pf = nullptr;
    int fv = 0;
#define PREPOLL(PH)                                                          \
    do {                                                                     \
        pf = flg + ((bn + (PH) * 8 + (lane & 7)) & 31);                      \
        fv = __hip_atomic_load(pf, __ATOMIC_RELAXED, __HIP_MEMORY_SCOPE_AGENT); \
    } while (0)
#define CHECKF()                                                             \
    while (!__all(fv != 0)) {                                                \
        __builtin_amdgcn_s_sleep(1);                                         \
        fv = __hip_atomic_load(pf, __ATOMIC_RELAXED, __HIP_MEMORY_SCOPE_AGENT); \
    }

#define ITER(ISS, J, CMP)                                                    \
    do { wait_vm_barrier<24>(); ISSUE_AB(ISS, J); COMPUTE(CMP); } while (0)

    // epilogue constants (step-invariant)
    float wv[2], bv[2];
    int xbase[4];
#pragma unroll
    for (int j = 0; j < 2; ++j) {
        const int col = bn * 64 + wn + j * 16 + fr;
        wv[j] = Whx[col];
        bv[j] = bh[col];
    }
#pragma unroll
    for (int i = 0; i < 4; ++i)
        xbase[i] = (bm * 128 + wm + i * 16 + fq * 4) * T_;

#pragma unroll 1
    for (int t = 1; t < T_; ++t) {
        const bf16_t* __restrict__ Abuf = g_hb[(t - 1) & 1];
        bf16_t* __restrict__ hn = g_hb[t & 1];
        const int* flg = g_flag + (t - 1) * 256 + bm * 32;

        // phase 0 (chunks 0..7): self chunk is first -> usually instant.
        PREPOLL(0); CHECKF();
        PREPOLL(1);                       // retired long before its CHECKF

        ISSUE_AB(0, 0); ISSUE_AB(1, 1); ISSUE_AB(2, 2);
        ISSUE_AB(3, 3); ISSUE_AB(4, 4);

        f32x4 acc[4][2];
#pragma unroll
        for (int i = 0; i < 4; ++i)
#pragma unroll
            for (int j = 0; j < 2; ++j) acc[i][j] = (f32x4)(0.f);

        // 32 chunks, 6-slot ring, 5 in flight, steady vmcnt(24).
        ITER(5, 5, 0);  ITER(0, 6, 1);  ITER(1, 7, 2);
        CHECKF();                                          // phase 1 gate
        ITER(2, 8, 3);  ITER(3, 9, 4);
        PREPOLL(2);
        ITER(4, 10, 5); ITER(5, 11, 0); ITER(0, 12, 1);
        ITER(1, 13, 2); ITER(2, 14, 3); ITER(3, 15, 4);
        CHECKF();                                          // phase 2 gate
        ITER(4, 16, 5); ITER(5, 17, 0);
        PREPOLL(3);
        ITER(0, 18, 1); ITER(1, 19, 2); ITER(2, 20, 3);
        ITER(3, 21, 4); ITER(4, 22, 5); ITER(5, 23, 0);
        CHECKF();                                          // phase 3 gate
        ITER(0, 24, 1); ITER(1, 25, 2); ITER(2, 26, 3);
        ITER(3, 27, 4); ITER(4, 28, 5); ITER(5, 29, 0);
        ITER(0, 30, 1); ITER(1, 31, 2);
        wait_vm_barrier<24>(); COMPUTE(3);                 // drain 27..31
        wait_vm_barrier<18>(); COMPUTE(4);
        wait_vm_barrier<12>(); COMPUTE(5);
        wait_vm_barrier<6>();  COMPUTE(0);
        wait_vm_barrier<0>();  COMPUTE(1);

        // epilogue: + x_t*W_hx + b_h, tanh, bf16 store
#pragma unroll
        for (int i = 0; i < 4; ++i) {
            const int row0 = bm * 128 + wm + i * 16 + fq * 4;
            float xv[4];
#pragma unroll
            for (int r = 0; r < 4; ++r) xv[r] = x[xbase[i] + r * T_ + t];
#pragma unroll
            for (int j = 0; j < 2; ++j) {
                const int col = bn * 64 + wn + j * 16 + fr;
#pragma unroll
                for (int r = 0; r < 4; ++r)
                    hn[(size_t)(row0 + r) * H_ + col] =
                        (bf16_t)tanhf(acc[i][j][r] + xv[r] * wv[j] + bv[j]);
            }
        }

        // publish: drain this wave's stores to L2, join waves, set own flag.
        asm volatile("s_waitcnt vmcnt(0)" ::: "memory");
        __syncthreads();
        if (tid == 0)
            __hip_atomic_store(&g_flag[t * 256 + bm * 32 + bn], 1,
                               __ATOMIC_RELAXED, __HIP_MEMORY_SCOPE_AGENT);
    }
#undef ITER
#undef CHECKF
#undef PREPOLL
#undef COMPUTE
#undef ISSUE_AB
}

// p = h_T @ W_ph + b_p : one wave per batch row, fp32 accumulate.
__global__ __launch_bounds__(64) void rnn_proj(const float* __restrict__ Wph,
                                               const float* __restrict__ bp,
                                               float* __restrict__ out, int sb) {
    const int b = blockIdx.x;
    const int l = threadIdx.x;
    const bf16_t* h = g_hb[sb] + (size_t)b * H_;
    float acc[C_];
#pragma unroll
    for (int c = 0; c < C_; ++c) acc[c] = 0.f;
    for (int k = l; k < H_; k += 64) {
        const float hv = (float)h[k];
#pragma unroll
        for (int c = 0; c < C_; ++c)
            acc[c] = fmaf(hv, Wph[k * C_ + c], acc[c]);
    }
#pragma unroll
    for (int off = 32; off > 0; off >>= 1)
#pragma unroll
        for (int c = 0; c < C_; ++c) acc[c] += __shfl_down(acc[c], off);
    if (l == 0) {
#pragma unroll
        for (int c = 0; c < C_; ++c) out[b * C_ + c] = acc[c] + bp[c];
    }
}

extern "C" void kernel_launch(void* const* d_in, const int* in_sizes, int n_in,
                              void* d_out, int out_size, void* d_ws, size_t ws_size,
                              hipStream_t stream) {
    const float* x   = (const float*)d_in[0];   // [1024,128]
    const float* Whx = (const float*)d_in[1];   // [1,2048]
    const float* Whh = (const float*)d_in[2];   // [2048,2048]
    const float* bh  = (const float*)d_in[3];   // [2048]
    const float* Wph = (const float*)d_in[4];   // [2048,10]
    const float* bp  = (const float*)d_in[5];   // [1,10]
    float* out = (float*)d_out;                 // [1024,10]

    static bool attr_set = false;
    if (!attr_set) {
        hipFuncSetAttribute((const void*)rnn_persist,
                            hipFuncAttributeMaxDynamicSharedMemorySize, 147456);
        attr_set = true;
    }

    prep_whhT<<<dim3(64, 64), 256, 0, stream>>>(Whh);
    rnn_init<<<(B_ * H_ / 4) / 256, 256, 0, stream>>>(x, Whx, bh);
    rnn_persist<<<256, 256, 147456, stream>>>(x, Whx, bh);
    rnn_proj<<<B_, 64, 0, stream>>>(Wph, bp, out, (T_ - 1) & 1);
}